// Round 8
// baseline (126.032 us; speedup 1.0000x reference)
//
#include <hip/hip_runtime.h>
#include <hip/hip_bf16.h>
#include <math.h>

#define NB 4
#define NT 4096
#define NC 1024
#define NH 64

typedef __attribute__((ext_vector_type(8))) short short8;
typedef __attribute__((ext_vector_type(4))) float f32x4;
typedef __attribute__((ext_vector_type(8))) unsigned short ushort8v;
typedef __attribute__((ext_vector_type(4))) unsigned short ushort4v;

static __device__ __forceinline__ unsigned short f2bf(float f) {
    union { __hip_bfloat16 b; unsigned short u; } cv;
    cv.b = __float2bfloat16(f);
    return cv.u;
}

// ---------------- W prep: Wt[m][h][k] bf16, m in {K,Q,V} ----------------
// Wq pre-scaled by 0.125*log2(e): QK^T scores land in log2 domain -> exp2.
__global__ __launch_bounds__(256) void wprep_kernel(
    const float* __restrict__ Wk,
    const float* __restrict__ Wq,
    const float* __restrict__ Wv,
    unsigned short* __restrict__ wt)
{
    __shared__ float tile[64][65];
    const int m  = blockIdx.x >> 4;
    const int k0 = (blockIdx.x & 15) << 6;
    const float* __restrict__ W = (m == 0) ? Wk : (m == 1) ? Wq : Wv;
    const float qs = (m == 1) ? 0.125f * 1.44269504f : 1.0f;
    const int tid = threadIdx.x;
    const int c   = tid & 63;
    for (int i = tid >> 6; i < 64; i += 4)
        tile[i][c] = W[(size_t)(k0 + i) * NH + c];
    __syncthreads();
    const int i0 = (tid >> 6) * 16;
    unsigned short* dst = wt + ((size_t)m * 64 + c) * NC + k0 + i0;
    ushort8v a, b;
#pragma unroll
    for (int j = 0; j < 8; ++j) a[j] = f2bf(tile[i0 + j][c] * qs);
#pragma unroll
    for (int j = 0; j < 8; ++j) b[j] = f2bf(tile[i0 + 8 + j][c] * qs);
    *reinterpret_cast<ushort8v*>(dst)     = a;
    *reinterpret_cast<ushort8v*>(dst + 8) = b;
}

// ---------------- projection GEMM, reg-staged bf16 LDS (unchanged R6) -----
__global__ __launch_bounds__(256, 2) void proj_kernel(
    const float* __restrict__ x,
    const unsigned short* __restrict__ wt,
    unsigned short* __restrict__ ko,
    unsigned short* __restrict__ qo,
    unsigned short* __restrict__ vt)
{
    __shared__ unsigned short xsb[2][32 * 64];

    const int tid  = threadIdx.x;
    const int wid  = tid >> 6;
    const int lane = tid & 63;
    const int l15  = lane & 15;
    const int hi   = lane >> 4;
    const int t0   = blockIdx.x << 5;

    const int srow = tid >> 3;
    const int sg   = tid & 7;
    const int ssw  = sg ^ (srow & 7);
    const float* __restrict__ xsrc = x + (size_t)(t0 + srow) * NC + sg * 8;
    unsigned short* const sdst0 = &xsb[0][srow * 64 + ssw * 8];
    unsigned short* const sdst1 = &xsb[1][srow * 64 + ssw * 8];

    const unsigned short* wp[3];
    int mm[3], hr[3];
#pragma unroll
    for (int f = 0; f < 3; ++f) {
        const int hc = wid * 48 + f * 16;
        mm[f] = hc >> 6;
        hr[f] = hc & 63;
        wp[f] = wt + ((size_t)(mm[f] * 64 + hr[f] + l15)) * NC + hi * 8;
    }

    f32x4 acc[2][3];
#pragma unroll
    for (int mf = 0; mf < 2; ++mf)
#pragma unroll
        for (int f = 0; f < 3; ++f) acc[mf][f] = (f32x4){0.f, 0.f, 0.f, 0.f};

    auto XWRITE = [&](unsigned short* dst, const f32x4& a, const f32x4& b) {
        ushort8v pk;
        pk[0] = f2bf(a[0]); pk[1] = f2bf(a[1]);
        pk[2] = f2bf(a[2]); pk[3] = f2bf(a[3]);
        pk[4] = f2bf(b[0]); pk[5] = f2bf(b[1]);
        pk[6] = f2bf(b[2]); pk[7] = f2bf(b[3]);
        *reinterpret_cast<ushort8v*>(dst) = pk;
    };

    auto COMPUTE = [&](int bi, int ck) {
        short8 xf[2][2];
#pragma unroll
        for (int mf = 0; mf < 2; ++mf) {
            const int row = mf * 16 + l15;
#pragma unroll
            for (int ks = 0; ks < 2; ++ks) {
                const int sw = (ks * 4 + hi) ^ (row & 7);
                xf[mf][ks] = *reinterpret_cast<const short8*>(
                    &xsb[bi][row * 64 + sw * 8]);
            }
        }
#pragma unroll
        for (int f = 0; f < 3; ++f) {
#pragma unroll
            for (int ks = 0; ks < 2; ++ks) {
                const short8 wf = *reinterpret_cast<const short8*>(
                    wp[f] + ck * 64 + ks * 32);
                if (mm[f] == 2) {
#pragma unroll
                    for (int mf = 0; mf < 2; ++mf)
                        acc[mf][f] = __builtin_amdgcn_mfma_f32_16x16x32_bf16(
                            xf[mf][ks], wf, acc[mf][f], 0, 0, 0);
                } else {
#pragma unroll
                    for (int mf = 0; mf < 2; ++mf)
                        acc[mf][f] = __builtin_amdgcn_mfma_f32_16x16x32_bf16(
                            wf, xf[mf][ks], acc[mf][f], 0, 0, 0);
                }
            }
        }
    };

    {
        const f32x4 a = *reinterpret_cast<const f32x4*>(xsrc);
        const f32x4 b = *reinterpret_cast<const f32x4*>(xsrc + 4);
        XWRITE(sdst0, a, b);
    }
    __syncthreads();

    for (int ck = 0; ck < 16; ++ck) {
        const int cur = ck & 1;
        f32x4 na, nb;
        if (ck < 15) {
            const float* p = xsrc + (ck + 1) * 64;
            na = *reinterpret_cast<const f32x4*>(p);
            nb = *reinterpret_cast<const f32x4*>(p + 4);
        }
        COMPUTE(cur, ck);
        if (ck < 15) XWRITE(cur ? sdst0 : sdst1, na, nb);
        __syncthreads();
    }

    const int b  = t0 >> 12;
    const int tl = t0 & (NT - 1);
#pragma unroll
    for (int f = 0; f < 3; ++f) {
#pragma unroll
        for (int mf = 0; mf < 2; ++mf) {
            const f32x4 a = acc[mf][f];
            ushort4v pk;
            pk[0] = f2bf(a[0]); pk[1] = f2bf(a[1]);
            pk[2] = f2bf(a[2]); pk[3] = f2bf(a[3]);
            if (mm[f] == 2) {
                unsigned short* d = vt + ((size_t)(b * NH + hr[f] + l15)) * NT
                                       + tl + mf * 16 + hi * 4;
                *reinterpret_cast<ushort4v*>(d) = pk;
            } else {
                unsigned short* o = (mm[f] == 0) ? ko : qo;
                unsigned short* d = o + (size_t)(t0 + mf * 16 + l15) * NH
                                      + hr[f] + hi * 4;
                *reinterpret_cast<ushort4v*>(d) = pk;
            }
        }
    }
}

// ---------------- MFMA causal flash attention, max-occupancy --------------
// One 16-row q-tile per block, 8 waves splitting the causal KV range.
// grid 1024 (heavy-first) x 512 thr -> 4 blocks/CU (35.8 KB LDS), 32 w/CU.
// p_lds is aliased into Of's storage (p_lds dead before Of is written;
// per-wave DS ops are in-order so no barrier needed inside a wave).
__global__ __launch_bounds__(512, 8) void attn_kernel(
    const unsigned short* __restrict__ kin,
    const unsigned short* __restrict__ qin,
    const unsigned short* __restrict__ vt,
    float* __restrict__ outp)
{
    __shared__ float Of[8][16][68];     // 34.8 KB; KV-loop: aliased as p_lds
    __shared__ float Ml[8][16][2];      // 1 KB

    const int tid  = threadIdx.x;
    const int wid  = tid >> 6;
    const int lane = tid & 63;
    const int q15  = lane & 15;
    const int hi   = lane >> 4;

    const int qt = 255 - (blockIdx.x >> 2);   // heavy-first
    const int b  = blockIdx.x & 3;
    const int q0 = qt << 4;
    const int gq = q0 + q15;

    // per-wave P scratch inside Of[wid] (16 rows x 72 ushorts = 2304 B < 4352)
    unsigned short* const p_base = reinterpret_cast<unsigned short*>(&Of[wid][0][0]);

    const int n  = (qt >> 2) + 1;
    const int base = n >> 3, rem = n & 7;
    const int start = wid * base + min(wid, rem);
    const int cnt   = base + (wid < rem ? 1 : 0);

    const unsigned short* kb = kin + (size_t)b * NT * NH;
    const unsigned short* qb = qin + (size_t)b * NT * NH;
    const unsigned short* vb = vt  + (size_t)b * NH * NT;

    short8 qf0, qf1;
    {
        const unsigned short* qrow = qb + (size_t)gq * NH + hi * 8;
        qf0 = *reinterpret_cast<const short8*>(qrow);
        qf1 = *reinterpret_cast<const short8*>(qrow + 32);
    }

    f32x4 ot[4];
#pragma unroll
    for (int i = 0; i < 4; ++i) ot[i] = (f32x4){0.f, 0.f, 0.f, 0.f};
    float m = 0.f, lp = 0.f;              // defer-max; log2 domain

    for (int jb = start; jb < start + cnt; ++jb) {
        const int kv0 = jb << 6;

        // ---- S^T = K . Q^T ----
        f32x4 st[4];
#pragma unroll
        for (int kt = 0; kt < 4; ++kt) {
            const unsigned short* krow =
                kb + (size_t)(kv0 + kt * 16 + q15) * NH + hi * 8;
            const short8 ka0 = *reinterpret_cast<const short8*>(krow);
            const short8 ka1 = *reinterpret_cast<const short8*>(krow + 32);
            f32x4 acc = (f32x4){0.f, 0.f, 0.f, 0.f};
            acc = __builtin_amdgcn_mfma_f32_16x16x32_bf16(ka0, qf0, acc, 0, 0, 0);
            acc = __builtin_amdgcn_mfma_f32_16x16x32_bf16(ka1, qf1, acc, 0, 0, 0);
            st[kt] = acc;
        }

        // ---- mask (diagonal only) + per-lane max ----
        float tmax4 = -INFINITY;
        if (jb == n - 1) {
#pragma unroll
            for (int kt = 0; kt < 4; ++kt)
#pragma unroll
                for (int r = 0; r < 4; ++r) {
                    const int gk = kv0 + kt * 16 + hi * 4 + r;
                    const float s = (gk <= gq) ? st[kt][r] : -INFINITY;
                    st[kt][r] = s;
                    tmax4 = fmaxf(tmax4, s);
                }
        } else {
#pragma unroll
            for (int kt = 0; kt < 4; ++kt)
#pragma unroll
                for (int r = 0; r < 4; ++r)
                    tmax4 = fmaxf(tmax4, st[kt][r]);
        }

        // ---- defer-max rescale (rare) ----
        if (!__all(tmax4 <= m + 11.5f)) {
            float tm = fmaxf(tmax4, __shfl_xor(tmax4, 16));
            tm = fmaxf(tm, __shfl_xor(tm, 32));
            const float mnew = fmaxf(m, tm);
            const float corr = __builtin_amdgcn_exp2f(m - mnew);
            lp *= corr;
#pragma unroll
            for (int i = 0; i < 4; ++i) {
                ot[i][0] *= corr; ot[i][1] *= corr;
                ot[i][2] *= corr; ot[i][3] *= corr;
            }
            m = mnew;
        }

        // ---- P = exp2(S - m) -> LDS (bf16); per-lane l ----
#pragma unroll
        for (int kt = 0; kt < 4; ++kt) {
            const float p0 = __builtin_amdgcn_exp2f(st[kt][0] - m);
            const float p1 = __builtin_amdgcn_exp2f(st[kt][1] - m);
            const float p2 = __builtin_amdgcn_exp2f(st[kt][2] - m);
            const float p3 = __builtin_amdgcn_exp2f(st[kt][3] - m);
            lp += (p0 + p1) + (p2 + p3);
            ushort4v pk;
            pk[0] = f2bf(p0); pk[1] = f2bf(p1);
            pk[2] = f2bf(p2); pk[3] = f2bf(p3);
            *reinterpret_cast<ushort4v*>(p_base + q15 * 72 + kt * 16 + hi * 4) = pk;
        }

        // ---- O^T += V^T . P^T ----
        const short8 pb0 = *reinterpret_cast<const short8*>(p_base + q15 * 72 + hi * 8);
        const short8 pb1 = *reinterpret_cast<const short8*>(p_base + q15 * 72 + 32 + hi * 8);
#pragma unroll
        for (int ht = 0; ht < 4; ++ht) {
            const unsigned short* vrow =
                vb + (size_t)(ht * 16 + q15) * NT + kv0 + hi * 8;
            const short8 va0 = *reinterpret_cast<const short8*>(vrow);
            const short8 va1 = *reinterpret_cast<const short8*>(vrow + 32);
            ot[ht] = __builtin_amdgcn_mfma_f32_16x16x32_bf16(va0, pb0, ot[ht], 0, 0, 0);
            ot[ht] = __builtin_amdgcn_mfma_f32_16x16x32_bf16(va1, pb1, ot[ht], 0, 0, 0);
        }
    }

    // ---- per-lane l -> per-row l; stash partials (overwrites p_lds) ----
    float l = lp + __shfl_xor(lp, 16);
    l += __shfl_xor(l, 32);
    if (hi == 0) { Ml[wid][q15][0] = m; Ml[wid][q15][1] = l; }
#pragma unroll
    for (int ht = 0; ht < 4; ++ht)
        *reinterpret_cast<f32x4*>(&Of[wid][q15][ht * 16 + hi * 4]) = ot[ht];
    __syncthreads();

    // ---- combine 8 wave-partials, write O ----
    {
        const int r  = tid >> 5;
        const int h0 = (tid & 31) * 2;
        float mg = Ml[0][r][0];
#pragma unroll
        for (int w = 1; w < 8; ++w) mg = fmaxf(mg, Ml[w][r][0]);
        float L = 0.f, o0 = 0.f, o1 = 0.f;
#pragma unroll
        for (int w = 0; w < 8; ++w) {
            const float ww = __builtin_amdgcn_exp2f(Ml[w][r][0] - mg);
            L  += ww * Ml[w][r][1];
            o0 += ww * Of[w][r][h0];
            o1 += ww * Of[w][r][h0 + 1];
        }
        const float invL = 1.f / L;
        float* od = outp + ((size_t)b * NT + q0 + r) * NH + h0;
        od[0] = o0 * invL;
        od[1] = o1 * invL;
    }
}

extern "C" void kernel_launch(void* const* d_in, const int* in_sizes, int n_in,
                              void* d_out, int out_size, void* d_ws, size_t ws_size,
                              hipStream_t stream) {
    const float* x  = (const float*)d_in[0];
    const float* Wk = (const float*)d_in[1];
    const float* Wq = (const float*)d_in[2];
    const float* Wv = (const float*)d_in[3];
    float* out = (float*)d_out;

    unsigned short* kbuf = (unsigned short*)d_ws;              // [B*T][64] bf16
    unsigned short* qbuf = kbuf + (size_t)NB * NT * NH;        // [B*T][64] bf16
    unsigned short* vtbf = qbuf + (size_t)NB * NT * NH;        // [B][64][T] bf16
    unsigned short* wtbf = vtbf + (size_t)NB * NT * NH;        // [3][64][1024] bf16

    wprep_kernel<<<48, 256, 0, stream>>>(Wk, Wq, Wv, wtbf);
    proj_kernel<<<NB * NT / 32, 256, 0, stream>>>(x, wtbf, kbuf, qbuf, vtbf);
    attn_kernel<<<256 * NB, 512, 0, stream>>>(kbuf, qbuf, vtbf, out);
}

// Round 9
// 109.556 us; speedup vs baseline: 1.1504x; 1.1504x over previous
//
#include <hip/hip_runtime.h>
#include <hip/hip_bf16.h>
#include <math.h>

#define NB 4
#define NT 4096
#define NC 1024
#define NH 64

typedef __attribute__((ext_vector_type(8))) short short8;
typedef __attribute__((ext_vector_type(4))) float f32x4;
typedef __attribute__((ext_vector_type(8))) unsigned short ushort8v;
typedef __attribute__((ext_vector_type(4))) unsigned short ushort4v;

static __device__ __forceinline__ unsigned short f2bf(float f) {
    union { __hip_bfloat16 b; unsigned short u; } cv;
    cv.b = __float2bfloat16(f);
    return cv.u;
}

// ---------------- W prep: Wt[m][h][k] bf16, m in {K,Q,V} ----------------
// Wq pre-scaled by 0.125*log2(e): QK^T scores land in log2 domain -> exp2.
__global__ __launch_bounds__(256) void wprep_kernel(
    const float* __restrict__ Wk,
    const float* __restrict__ Wq,
    const float* __restrict__ Wv,
    unsigned short* __restrict__ wt)
{
    __shared__ float tile[64][65];
    const int m  = blockIdx.x >> 4;
    const int k0 = (blockIdx.x & 15) << 6;
    const float* __restrict__ W = (m == 0) ? Wk : (m == 1) ? Wq : Wv;
    const float qs = (m == 1) ? 0.125f * 1.44269504f : 1.0f;
    const int tid = threadIdx.x;
    const int c   = tid & 63;
    for (int i = tid >> 6; i < 64; i += 4)
        tile[i][c] = W[(size_t)(k0 + i) * NH + c];
    __syncthreads();
    const int i0 = (tid >> 6) * 16;
    unsigned short* dst = wt + ((size_t)m * 64 + c) * NC + k0 + i0;
    ushort8v a, b;
#pragma unroll
    for (int j = 0; j < 8; ++j) a[j] = f2bf(tile[i0 + j][c] * qs);
#pragma unroll
    for (int j = 0; j < 8; ++j) b[j] = f2bf(tile[i0 + 8 + j][c] * qs);
    *reinterpret_cast<ushort8v*>(dst)     = a;
    *reinterpret_cast<ushort8v*>(dst + 8) = b;
}

// ---------------- projection GEMM, reg-staged bf16 LDS (unchanged) --------
__global__ __launch_bounds__(256, 2) void proj_kernel(
    const float* __restrict__ x,
    const unsigned short* __restrict__ wt,
    unsigned short* __restrict__ ko,
    unsigned short* __restrict__ qo,
    unsigned short* __restrict__ vt)
{
    __shared__ unsigned short xsb[2][32 * 64];

    const int tid  = threadIdx.x;
    const int wid  = tid >> 6;
    const int lane = tid & 63;
    const int l15  = lane & 15;
    const int hi   = lane >> 4;
    const int t0   = blockIdx.x << 5;

    const int srow = tid >> 3;
    const int sg   = tid & 7;
    const int ssw  = sg ^ (srow & 7);
    const float* __restrict__ xsrc = x + (size_t)(t0 + srow) * NC + sg * 8;
    unsigned short* const sdst0 = &xsb[0][srow * 64 + ssw * 8];
    unsigned short* const sdst1 = &xsb[1][srow * 64 + ssw * 8];

    const unsigned short* wp[3];
    int mm[3], hr[3];
#pragma unroll
    for (int f = 0; f < 3; ++f) {
        const int hc = wid * 48 + f * 16;
        mm[f] = hc >> 6;
        hr[f] = hc & 63;
        wp[f] = wt + ((size_t)(mm[f] * 64 + hr[f] + l15)) * NC + hi * 8;
    }

    f32x4 acc[2][3];
#pragma unroll
    for (int mf = 0; mf < 2; ++mf)
#pragma unroll
        for (int f = 0; f < 3; ++f) acc[mf][f] = (f32x4){0.f, 0.f, 0.f, 0.f};

    auto XWRITE = [&](unsigned short* dst, const f32x4& a, const f32x4& b) {
        ushort8v pk;
        pk[0] = f2bf(a[0]); pk[1] = f2bf(a[1]);
        pk[2] = f2bf(a[2]); pk[3] = f2bf(a[3]);
        pk[4] = f2bf(b[0]); pk[5] = f2bf(b[1]);
        pk[6] = f2bf(b[2]); pk[7] = f2bf(b[3]);
        *reinterpret_cast<ushort8v*>(dst) = pk;
    };

    auto COMPUTE = [&](int bi, int ck) {
        short8 xf[2][2];
#pragma unroll
        for (int mf = 0; mf < 2; ++mf) {
            const int row = mf * 16 + l15;
#pragma unroll
            for (int ks = 0; ks < 2; ++ks) {
                const int sw = (ks * 4 + hi) ^ (row & 7);
                xf[mf][ks] = *reinterpret_cast<const short8*>(
                    &xsb[bi][row * 64 + sw * 8]);
            }
        }
#pragma unroll
        for (int f = 0; f < 3; ++f) {
#pragma unroll
            for (int ks = 0; ks < 2; ++ks) {
                const short8 wf = *reinterpret_cast<const short8*>(
                    wp[f] + ck * 64 + ks * 32);
                if (mm[f] == 2) {
#pragma unroll
                    for (int mf = 0; mf < 2; ++mf)
                        acc[mf][f] = __builtin_amdgcn_mfma_f32_16x16x32_bf16(
                            xf[mf][ks], wf, acc[mf][f], 0, 0, 0);
                } else {
#pragma unroll
                    for (int mf = 0; mf < 2; ++mf)
                        acc[mf][f] = __builtin_amdgcn_mfma_f32_16x16x32_bf16(
                            wf, xf[mf][ks], acc[mf][f], 0, 0, 0);
                }
            }
        }
    };

    {
        const f32x4 a = *reinterpret_cast<const f32x4*>(xsrc);
        const f32x4 b = *reinterpret_cast<const f32x4*>(xsrc + 4);
        XWRITE(sdst0, a, b);
    }
    __syncthreads();

    for (int ck = 0; ck < 16; ++ck) {
        const int cur = ck & 1;
        f32x4 na, nb;
        if (ck < 15) {
            const float* p = xsrc + (ck + 1) * 64;
            na = *reinterpret_cast<const f32x4*>(p);
            nb = *reinterpret_cast<const f32x4*>(p + 4);
        }
        COMPUTE(cur, ck);
        if (ck < 15) XWRITE(cur ? sdst0 : sdst1, na, nb);
        __syncthreads();
    }

    const int b  = t0 >> 12;
    const int tl = t0 & (NT - 1);
#pragma unroll
    for (int f = 0; f < 3; ++f) {
#pragma unroll
        for (int mf = 0; mf < 2; ++mf) {
            const f32x4 a = acc[mf][f];
            ushort4v pk;
            pk[0] = f2bf(a[0]); pk[1] = f2bf(a[1]);
            pk[2] = f2bf(a[2]); pk[3] = f2bf(a[3]);
            if (mm[f] == 2) {
                unsigned short* d = vt + ((size_t)(b * NH + hr[f] + l15)) * NT
                                       + tl + mf * 16 + hi * 4;
                *reinterpret_cast<ushort4v*>(d) = pk;
            } else {
                unsigned short* o = (mm[f] == 0) ? ko : qo;
                unsigned short* d = o + (size_t)(t0 + mf * 16 + l15) * NH
                                      + hr[f] + hi * 4;
                *reinterpret_cast<ushort4v*>(d) = pk;
            }
        }
    }
}

// ---------------- MFMA causal flash attention, max-occupancy --------------
// One 16-row q-tile per block, 8 waves splitting the causal KV range.
// grid 1024 (heavy-first) x 512 thr. LDS 35.8 KB -> 4 blocks/CU; VGPR ~52
// -> 8 waves/SIMD -> 32 waves/CU. Bound (512,4): VGPR budget 128, NO spill
// (R7's (512,8) forced <=64 VGPR -> scratch spill -> 20 MB HBM writes).
__global__ __launch_bounds__(512, 4) void attn_kernel(
    const unsigned short* __restrict__ kin,
    const unsigned short* __restrict__ qin,
    const unsigned short* __restrict__ vt,
    float* __restrict__ outp)
{
    __shared__ float Of[8][16][68];     // 34.8 KB; KV-loop: aliased as p_lds
    __shared__ float Ml[8][16][2];      // 1 KB

    const int tid  = threadIdx.x;
    const int wid  = tid >> 6;
    const int lane = tid & 63;
    const int q15  = lane & 15;
    const int hi   = lane >> 4;

    const int qt = 255 - (blockIdx.x >> 2);   // heavy-first
    const int b  = blockIdx.x & 3;
    const int q0 = qt << 4;
    const int gq = q0 + q15;

    // per-wave P scratch inside Of[wid] (16 rows x 72 ushorts = 2304 B < 4352)
    unsigned short* const p_base = reinterpret_cast<unsigned short*>(&Of[wid][0][0]);

    const int n  = (qt >> 2) + 1;
    const int base = n >> 3, rem = n & 7;
    const int start = wid * base + min(wid, rem);
    const int cnt   = base + (wid < rem ? 1 : 0);

    const unsigned short* kb = kin + (size_t)b * NT * NH;
    const unsigned short* qb = qin + (size_t)b * NT * NH;
    const unsigned short* vb = vt  + (size_t)b * NH * NT;

    short8 qf0, qf1;
    {
        const unsigned short* qrow = qb + (size_t)gq * NH + hi * 8;
        qf0 = *reinterpret_cast<const short8*>(qrow);
        qf1 = *reinterpret_cast<const short8*>(qrow + 32);
    }

    f32x4 ot[4];
#pragma unroll
    for (int i = 0; i < 4; ++i) ot[i] = (f32x4){0.f, 0.f, 0.f, 0.f};
    float m = 0.f, lp = 0.f;              // defer-max; log2 domain

    for (int jb = start; jb < start + cnt; ++jb) {
        const int kv0 = jb << 6;

        // ---- S^T = K . Q^T ----
        f32x4 st[4];
#pragma unroll
        for (int kt = 0; kt < 4; ++kt) {
            const unsigned short* krow =
                kb + (size_t)(kv0 + kt * 16 + q15) * NH + hi * 8;
            const short8 ka0 = *reinterpret_cast<const short8*>(krow);
            const short8 ka1 = *reinterpret_cast<const short8*>(krow + 32);
            f32x4 acc = (f32x4){0.f, 0.f, 0.f, 0.f};
            acc = __builtin_amdgcn_mfma_f32_16x16x32_bf16(ka0, qf0, acc, 0, 0, 0);
            acc = __builtin_amdgcn_mfma_f32_16x16x32_bf16(ka1, qf1, acc, 0, 0, 0);
            st[kt] = acc;
        }

        // ---- mask (diagonal only) + per-lane max ----
        float tmax4 = -INFINITY;
        if (jb == n - 1) {
#pragma unroll
            for (int kt = 0; kt < 4; ++kt)
#pragma unroll
                for (int r = 0; r < 4; ++r) {
                    const int gk = kv0 + kt * 16 + hi * 4 + r;
                    const float s = (gk <= gq) ? st[kt][r] : -INFINITY;
                    st[kt][r] = s;
                    tmax4 = fmaxf(tmax4, s);
                }
        } else {
#pragma unroll
            for (int kt = 0; kt < 4; ++kt)
#pragma unroll
                for (int r = 0; r < 4; ++r)
                    tmax4 = fmaxf(tmax4, st[kt][r]);
        }

        // ---- defer-max rescale (rare) ----
        if (!__all(tmax4 <= m + 11.5f)) {
            float tm = fmaxf(tmax4, __shfl_xor(tmax4, 16));
            tm = fmaxf(tm, __shfl_xor(tm, 32));
            const float mnew = fmaxf(m, tm);
            const float corr = __builtin_amdgcn_exp2f(m - mnew);
            lp *= corr;
#pragma unroll
            for (int i = 0; i < 4; ++i) {
                ot[i][0] *= corr; ot[i][1] *= corr;
                ot[i][2] *= corr; ot[i][3] *= corr;
            }
            m = mnew;
        }

        // ---- P = exp2(S - m) -> LDS (bf16); per-lane l ----
#pragma unroll
        for (int kt = 0; kt < 4; ++kt) {
            const float p0 = __builtin_amdgcn_exp2f(st[kt][0] - m);
            const float p1 = __builtin_amdgcn_exp2f(st[kt][1] - m);
            const float p2 = __builtin_amdgcn_exp2f(st[kt][2] - m);
            const float p3 = __builtin_amdgcn_exp2f(st[kt][3] - m);
            lp += (p0 + p1) + (p2 + p3);
            ushort4v pk;
            pk[0] = f2bf(p0); pk[1] = f2bf(p1);
            pk[2] = f2bf(p2); pk[3] = f2bf(p3);
            *reinterpret_cast<ushort4v*>(p_base + q15 * 72 + kt * 16 + hi * 4) = pk;
        }

        // ---- O^T += V^T . P^T ----
        const short8 pb0 = *reinterpret_cast<const short8*>(p_base + q15 * 72 + hi * 8);
        const short8 pb1 = *reinterpret_cast<const short8*>(p_base + q15 * 72 + 32 + hi * 8);
#pragma unroll
        for (int ht = 0; ht < 4; ++ht) {
            const unsigned short* vrow =
                vb + (size_t)(ht * 16 + q15) * NT + kv0 + hi * 8;
            const short8 va0 = *reinterpret_cast<const short8*>(vrow);
            const short8 va1 = *reinterpret_cast<const short8*>(vrow + 32);
            ot[ht] = __builtin_amdgcn_mfma_f32_16x16x32_bf16(va0, pb0, ot[ht], 0, 0, 0);
            ot[ht] = __builtin_amdgcn_mfma_f32_16x16x32_bf16(va1, pb1, ot[ht], 0, 0, 0);
        }
    }

    // ---- per-lane l -> per-row l; stash partials (overwrites p_lds) ----
    float l = lp + __shfl_xor(lp, 16);
    l += __shfl_xor(l, 32);
    if (hi == 0) { Ml[wid][q15][0] = m; Ml[wid][q15][1] = l; }
#pragma unroll
    for (int ht = 0; ht < 4; ++ht)
        *reinterpret_cast<f32x4*>(&Of[wid][q15][ht * 16 + hi * 4]) = ot[ht];
    __syncthreads();

    // ---- combine 8 wave-partials, write O ----
    {
        const int r  = tid >> 5;
        const int h0 = (tid & 31) * 2;
        float mg = Ml[0][r][0];
#pragma unroll
        for (int w = 1; w < 8; ++w) mg = fmaxf(mg, Ml[w][r][0]);
        float L = 0.f, o0 = 0.f, o1 = 0.f;
#pragma unroll
        for (int w = 0; w < 8; ++w) {
            const float ww = __builtin_amdgcn_exp2f(Ml[w][r][0] - mg);
            L  += ww * Ml[w][r][1];
            o0 += ww * Of[w][r][h0];
            o1 += ww * Of[w][r][h0 + 1];
        }
        const float invL = 1.f / L;
        float* od = outp + ((size_t)b * NT + q0 + r) * NH + h0;
        od[0] = o0 * invL;
        od[1] = o1 * invL;
    }
}

extern "C" void kernel_launch(void* const* d_in, const int* in_sizes, int n_in,
                              void* d_out, int out_size, void* d_ws, size_t ws_size,
                              hipStream_t stream) {
    const float* x  = (const float*)d_in[0];
    const float* Wk = (const float*)d_in[1];
    const float* Wq = (const float*)d_in[2];
    const float* Wv = (const float*)d_in[3];
    float* out = (float*)d_out;

    unsigned short* kbuf = (unsigned short*)d_ws;              // [B*T][64] bf16
    unsigned short* qbuf = kbuf + (size_t)NB * NT * NH;        // [B*T][64] bf16
    unsigned short* vtbf = qbuf + (size_t)NB * NT * NH;        // [B][64][T] bf16
    unsigned short* wtbf = vtbf + (size_t)NB * NT * NH;        // [3][64][1024] bf16

    wprep_kernel<<<48, 256, 0, stream>>>(Wk, Wq, Wv, wtbf);
    proj_kernel<<<NB * NT / 32, 256, 0, stream>>>(x, wtbf, kbuf, qbuf, vtbf);
    attn_kernel<<<256 * NB, 512, 0, stream>>>(kbuf, qbuf, vtbf, out);
}

// Round 10
// 108.718 us; speedup vs baseline: 1.1593x; 1.0077x over previous
//
#include <hip/hip_runtime.h>
#include <hip/hip_bf16.h>
#include <math.h>

#define NB 4
#define NT 4096
#define NC 1024
#define NH 64

typedef __attribute__((ext_vector_type(8))) short short8;
typedef __attribute__((ext_vector_type(4))) float f32x4;
typedef __attribute__((ext_vector_type(8))) unsigned short ushort8v;
typedef __attribute__((ext_vector_type(4))) unsigned short ushort4v;

static __device__ __forceinline__ unsigned short f2bf(float f) {
    union { __hip_bfloat16 b; unsigned short u; } cv;
    cv.b = __float2bfloat16(f);
    return cv.u;
}

// ---------------- W prep: Wt[m][h][k] bf16, m in {K,Q,V} ----------------
// Wq pre-scaled by 0.125*log2(e): QK^T scores land in log2 domain -> exp2.
__global__ __launch_bounds__(256) void wprep_kernel(
    const float* __restrict__ Wk,
    const float* __restrict__ Wq,
    const float* __restrict__ Wv,
    unsigned short* __restrict__ wt)
{
    __shared__ float tile[64][65];
    const int m  = blockIdx.x >> 4;
    const int k0 = (blockIdx.x & 15) << 6;
    const float* __restrict__ W = (m == 0) ? Wk : (m == 1) ? Wq : Wv;
    const float qs = (m == 1) ? 0.125f * 1.44269504f : 1.0f;
    const int tid = threadIdx.x;
    const int c   = tid & 63;
    for (int i = tid >> 6; i < 64; i += 4)
        tile[i][c] = W[(size_t)(k0 + i) * NH + c];
    __syncthreads();
    const int i0 = (tid >> 6) * 16;
    unsigned short* dst = wt + ((size_t)m * 64 + c) * NC + k0 + i0;
    ushort8v a, b;
#pragma unroll
    for (int j = 0; j < 8; ++j) a[j] = f2bf(tile[i0 + j][c] * qs);
#pragma unroll
    for (int j = 0; j < 8; ++j) b[j] = f2bf(tile[i0 + 8 + j][c] * qs);
    *reinterpret_cast<ushort8v*>(dst)     = a;
    *reinterpret_cast<ushort8v*>(dst + 8) = b;
}

// ---------------- projection GEMM, reg-staged bf16 LDS (unchanged) --------
__global__ __launch_bounds__(256, 2) void proj_kernel(
    const float* __restrict__ x,
    const unsigned short* __restrict__ wt,
    unsigned short* __restrict__ ko,
    unsigned short* __restrict__ qo,
    unsigned short* __restrict__ vt)
{
    __shared__ unsigned short xsb[2][32 * 64];

    const int tid  = threadIdx.x;
    const int wid  = tid >> 6;
    const int lane = tid & 63;
    const int l15  = lane & 15;
    const int hi   = lane >> 4;
    const int t0   = blockIdx.x << 5;

    const int srow = tid >> 3;
    const int sg   = tid & 7;
    const int ssw  = sg ^ (srow & 7);
    const float* __restrict__ xsrc = x + (size_t)(t0 + srow) * NC + sg * 8;
    unsigned short* const sdst0 = &xsb[0][srow * 64 + ssw * 8];
    unsigned short* const sdst1 = &xsb[1][srow * 64 + ssw * 8];

    const unsigned short* wp[3];
    int mm[3], hr[3];
#pragma unroll
    for (int f = 0; f < 3; ++f) {
        const int hc = wid * 48 + f * 16;
        mm[f] = hc >> 6;
        hr[f] = hc & 63;
        wp[f] = wt + ((size_t)(mm[f] * 64 + hr[f] + l15)) * NC + hi * 8;
    }

    f32x4 acc[2][3];
#pragma unroll
    for (int mf = 0; mf < 2; ++mf)
#pragma unroll
        for (int f = 0; f < 3; ++f) acc[mf][f] = (f32x4){0.f, 0.f, 0.f, 0.f};

    auto XWRITE = [&](unsigned short* dst, const f32x4& a, const f32x4& b) {
        ushort8v pk;
        pk[0] = f2bf(a[0]); pk[1] = f2bf(a[1]);
        pk[2] = f2bf(a[2]); pk[3] = f2bf(a[3]);
        pk[4] = f2bf(b[0]); pk[5] = f2bf(b[1]);
        pk[6] = f2bf(b[2]); pk[7] = f2bf(b[3]);
        *reinterpret_cast<ushort8v*>(dst) = pk;
    };

    auto COMPUTE = [&](int bi, int ck) {
        short8 xf[2][2];
#pragma unroll
        for (int mf = 0; mf < 2; ++mf) {
            const int row = mf * 16 + l15;
#pragma unroll
            for (int ks = 0; ks < 2; ++ks) {
                const int sw = (ks * 4 + hi) ^ (row & 7);
                xf[mf][ks] = *reinterpret_cast<const short8*>(
                    &xsb[bi][row * 64 + sw * 8]);
            }
        }
#pragma unroll
        for (int f = 0; f < 3; ++f) {
#pragma unroll
            for (int ks = 0; ks < 2; ++ks) {
                const short8 wf = *reinterpret_cast<const short8*>(
                    wp[f] + ck * 64 + ks * 32);
                if (mm[f] == 2) {
#pragma unroll
                    for (int mf = 0; mf < 2; ++mf)
                        acc[mf][f] = __builtin_amdgcn_mfma_f32_16x16x32_bf16(
                            xf[mf][ks], wf, acc[mf][f], 0, 0, 0);
                } else {
#pragma unroll
                    for (int mf = 0; mf < 2; ++mf)
                        acc[mf][f] = __builtin_amdgcn_mfma_f32_16x16x32_bf16(
                            wf, xf[mf][ks], acc[mf][f], 0, 0, 0);
                }
            }
        }
    };

    {
        const f32x4 a = *reinterpret_cast<const f32x4*>(xsrc);
        const f32x4 b = *reinterpret_cast<const f32x4*>(xsrc + 4);
        XWRITE(sdst0, a, b);
    }
    __syncthreads();

    for (int ck = 0; ck < 16; ++ck) {
        const int cur = ck & 1;
        f32x4 na, nb;
        if (ck < 15) {
            const float* p = xsrc + (ck + 1) * 64;
            na = *reinterpret_cast<const f32x4*>(p);
            nb = *reinterpret_cast<const f32x4*>(p + 4);
        }
        COMPUTE(cur, ck);
        if (ck < 15) XWRITE(cur ? sdst0 : sdst1, na, nb);
        __syncthreads();
    }

    const int b  = t0 >> 12;
    const int tl = t0 & (NT - 1);
#pragma unroll
    for (int f = 0; f < 3; ++f) {
#pragma unroll
        for (int mf = 0; mf < 2; ++mf) {
            const f32x4 a = acc[mf][f];
            ushort4v pk;
            pk[0] = f2bf(a[0]); pk[1] = f2bf(a[1]);
            pk[2] = f2bf(a[2]); pk[3] = f2bf(a[3]);
            if (mm[f] == 2) {
                unsigned short* d = vt + ((size_t)(b * NH + hr[f] + l15)) * NT
                                       + tl + mf * 16 + hi * 4;
                *reinterpret_cast<ushort4v*>(d) = pk;
            } else {
                unsigned short* o = (mm[f] == 0) ? ko : qo;
                unsigned short* d = o + (size_t)(t0 + mf * 16 + l15) * NH
                                      + hr[f] + hi * 4;
                *reinterpret_cast<ushort4v*>(d) = pk;
            }
        }
    }
}

// ---------------- MFMA causal flash attention, reg-prefetched -------------
// One 16-row q-tile per block, 8 waves splitting the causal KV range.
// T14 prefetch: current tile's V loads issued BEFORE QK^T; next tile's K
// loads issued right after QK^T consumes current K. Softmax + MFMA issue
// covers the L2 latency that previously serialized (~20k cyc/tile).
// XCD-batch affinity: XCD = bid%8 (round-robin dispatch), batch = xcd/2
// -> each XCD's L2 holds ONE batch's K/V/Q (~1.5 MB, L2-resident).
__global__ __launch_bounds__(512, 4) void attn_kernel(
    const unsigned short* __restrict__ kin,
    const unsigned short* __restrict__ qin,
    const unsigned short* __restrict__ vt,
    float* __restrict__ outp)
{
    __shared__ float Of[8][16][68];     // 34.8 KB; KV-loop: aliased as p_lds
    __shared__ float Ml[8][16][2];      // 1 KB

    const int tid  = threadIdx.x;
    const int wid  = tid >> 6;
    const int lane = tid & 63;
    const int q15  = lane & 15;
    const int hi   = lane >> 4;

    const int bid = blockIdx.x;
    const int b   = (bid & 7) >> 1;                    // batch pinned to XCD pair
    const int qt  = 255 - (((bid >> 3) << 1) | (bid & 1));  // heavy-first per XCD
    const int q0 = qt << 4;
    const int gq = q0 + q15;

    unsigned short* const p_base = reinterpret_cast<unsigned short*>(&Of[wid][0][0]);

    const int n  = (qt >> 2) + 1;
    const int base = n >> 3, rem = n & 7;
    const int start = wid * base + min(wid, rem);
    const int cnt   = base + (wid < rem ? 1 : 0);
    const int jend  = start + cnt;

    const unsigned short* kb = kin + (size_t)b * NT * NH;
    const unsigned short* qb = qin + (size_t)b * NT * NH;
    const unsigned short* vb = vt  + (size_t)b * NH * NT;

    short8 qf0, qf1;
    {
        const unsigned short* qrow = qb + (size_t)gq * NH + hi * 8;
        qf0 = *reinterpret_cast<const short8*>(qrow);
        qf1 = *reinterpret_cast<const short8*>(qrow + 32);
    }

    f32x4 ot[4];
#pragma unroll
    for (int i = 0; i < 4; ++i) ot[i] = (f32x4){0.f, 0.f, 0.f, 0.f};
    float m = 0.f, lp = 0.f;              // defer-max; log2 domain

    short8 kn[4][2];                      // prefetched K (next tile)
    if (cnt > 0) {
        const int kv0 = start << 6;
#pragma unroll
        for (int kt = 0; kt < 4; ++kt) {
            const unsigned short* kr = kb + (size_t)(kv0 + kt * 16 + q15) * NH + hi * 8;
            kn[kt][0] = *reinterpret_cast<const short8*>(kr);
            kn[kt][1] = *reinterpret_cast<const short8*>(kr + 32);
        }
    }

    for (int jb = start; jb < jend; ++jb) {
        const int kv0 = jb << 6;

        // ---- V loads for THIS tile, issued early (cover under QK^T+softmax)
        short8 vv[4][2];
#pragma unroll
        for (int ht = 0; ht < 4; ++ht) {
            const unsigned short* vr = vb + (size_t)(ht * 16 + q15) * NT + kv0 + hi * 8;
            vv[ht][0] = *reinterpret_cast<const short8*>(vr);
            vv[ht][1] = *reinterpret_cast<const short8*>(vr + 32);
        }

        // ---- S^T = K . Q^T (consumes kn) ----
        f32x4 st[4];
#pragma unroll
        for (int kt = 0; kt < 4; ++kt) {
            f32x4 acc = (f32x4){0.f, 0.f, 0.f, 0.f};
            acc = __builtin_amdgcn_mfma_f32_16x16x32_bf16(kn[kt][0], qf0, acc, 0, 0, 0);
            acc = __builtin_amdgcn_mfma_f32_16x16x32_bf16(kn[kt][1], qf1, acc, 0, 0, 0);
            st[kt] = acc;
        }

        // ---- prefetch NEXT tile's K (latency hidden under softmax+PV) ----
        if (jb + 1 < jend) {
            const int kv1 = (jb + 1) << 6;
#pragma unroll
            for (int kt = 0; kt < 4; ++kt) {
                const unsigned short* kr = kb + (size_t)(kv1 + kt * 16 + q15) * NH + hi * 8;
                kn[kt][0] = *reinterpret_cast<const short8*>(kr);
                kn[kt][1] = *reinterpret_cast<const short8*>(kr + 32);
            }
        }

        // ---- mask (diagonal only) + per-lane max ----
        float tmax4 = -INFINITY;
        if (jb == n - 1) {
#pragma unroll
            for (int kt = 0; kt < 4; ++kt)
#pragma unroll
                for (int r = 0; r < 4; ++r) {
                    const int gk = kv0 + kt * 16 + hi * 4 + r;
                    const float s = (gk <= gq) ? st[kt][r] : -INFINITY;
                    st[kt][r] = s;
                    tmax4 = fmaxf(tmax4, s);
                }
        } else {
#pragma unroll
            for (int kt = 0; kt < 4; ++kt)
#pragma unroll
                for (int r = 0; r < 4; ++r)
                    tmax4 = fmaxf(tmax4, st[kt][r]);
        }

        // ---- defer-max rescale (rare) ----
        if (!__all(tmax4 <= m + 11.5f)) {
            float tm = fmaxf(tmax4, __shfl_xor(tmax4, 16));
            tm = fmaxf(tm, __shfl_xor(tm, 32));
            const float mnew = fmaxf(m, tm);
            const float corr = __builtin_amdgcn_exp2f(m - mnew);
            lp *= corr;
#pragma unroll
            for (int i = 0; i < 4; ++i) {
                ot[i][0] *= corr; ot[i][1] *= corr;
                ot[i][2] *= corr; ot[i][3] *= corr;
            }
            m = mnew;
        }

        // ---- P = exp2(S - m) -> LDS (bf16); per-lane l ----
#pragma unroll
        for (int kt = 0; kt < 4; ++kt) {
            const float p0 = __builtin_amdgcn_exp2f(st[kt][0] - m);
            const float p1 = __builtin_amdgcn_exp2f(st[kt][1] - m);
            const float p2 = __builtin_amdgcn_exp2f(st[kt][2] - m);
            const float p3 = __builtin_amdgcn_exp2f(st[kt][3] - m);
            lp += (p0 + p1) + (p2 + p3);
            ushort4v pk;
            pk[0] = f2bf(p0); pk[1] = f2bf(p1);
            pk[2] = f2bf(p2); pk[3] = f2bf(p3);
            *reinterpret_cast<ushort4v*>(p_base + q15 * 72 + kt * 16 + hi * 4) = pk;
        }

        // ---- O^T += V^T . P^T (vv arrived long ago) ----
        const short8 pb0 = *reinterpret_cast<const short8*>(p_base + q15 * 72 + hi * 8);
        const short8 pb1 = *reinterpret_cast<const short8*>(p_base + q15 * 72 + 32 + hi * 8);
#pragma unroll
        for (int ht = 0; ht < 4; ++ht) {
            ot[ht] = __builtin_amdgcn_mfma_f32_16x16x32_bf16(vv[ht][0], pb0, ot[ht], 0, 0, 0);
            ot[ht] = __builtin_amdgcn_mfma_f32_16x16x32_bf16(vv[ht][1], pb1, ot[ht], 0, 0, 0);
        }
    }

    // ---- per-lane l -> per-row l; stash partials (overwrites p_lds) ----
    float l = lp + __shfl_xor(lp, 16);
    l += __shfl_xor(l, 32);
    if (hi == 0) { Ml[wid][q15][0] = m; Ml[wid][q15][1] = l; }
#pragma unroll
    for (int ht = 0; ht < 4; ++ht)
        *reinterpret_cast<f32x4*>(&Of[wid][q15][ht * 16 + hi * 4]) = ot[ht];
    __syncthreads();

    // ---- combine 8 wave-partials, write O ----
    {
        const int r  = tid >> 5;
        const int h0 = (tid & 31) * 2;
        float mg = Ml[0][r][0];
#pragma unroll
        for (int w = 1; w < 8; ++w) mg = fmaxf(mg, Ml[w][r][0]);
        float L = 0.f, o0 = 0.f, o1 = 0.f;
#pragma unroll
        for (int w = 0; w < 8; ++w) {
            const float ww = __builtin_amdgcn_exp2f(Ml[w][r][0] - mg);
            L  += ww * Ml[w][r][1];
            o0 += ww * Of[w][r][h0];
            o1 += ww * Of[w][r][h0 + 1];
        }
        const float invL = 1.f / L;
        float* od = outp + ((size_t)b * NT + q0 + r) * NH + h0;
        od[0] = o0 * invL;
        od[1] = o1 * invL;
    }
}

extern "C" void kernel_launch(void* const* d_in, const int* in_sizes, int n_in,
                              void* d_out, int out_size, void* d_ws, size_t ws_size,
                              hipStream_t stream) {
    const float* x  = (const float*)d_in[0];
    const float* Wk = (const float*)d_in[1];
    const float* Wq = (const float*)d_in[2];
    const float* Wv = (const float*)d_in[3];
    float* out = (float*)d_out;

    unsigned short* kbuf = (unsigned short*)d_ws;              // [B*T][64] bf16
    unsigned short* qbuf = kbuf + (size_t)NB * NT * NH;        // [B*T][64] bf16
    unsigned short* vtbf = qbuf + (size_t)NB * NT * NH;        // [B][64][T] bf16
    unsigned short* wtbf = vtbf + (size_t)NB * NT * NH;        // [3][64][1024] bf16

    wprep_kernel<<<48, 256, 0, stream>>>(Wk, Wq, Wv, wtbf);
    proj_kernel<<<NB * NT / 32, 256, 0, stream>>>(x, wtbf, kbuf, qbuf, vtbf);
    attn_kernel<<<256 * NB, 512, 0, stream>>>(kbuf, qbuf, vtbf, out);
}

// Round 11
// 85.089 us; speedup vs baseline: 1.4812x; 1.2777x over previous
//
#include <hip/hip_runtime.h>
#include <hip/hip_bf16.h>
#include <math.h>

#define NB 4
#define NT 4096
#define NC 1024
#define NH 64

typedef __attribute__((ext_vector_type(8))) short short8;
typedef __attribute__((ext_vector_type(4))) float f32x4;
typedef __attribute__((ext_vector_type(8))) unsigned short ushort8v;
typedef __attribute__((ext_vector_type(4))) unsigned short ushort4v;

static __device__ __forceinline__ unsigned short f2bf(float f) {
    union { __hip_bfloat16 b; unsigned short u; } cv;
    cv.b = __float2bfloat16(f);
    return cv.u;
}

// ---------------- W prep: Wt[m][h][k] bf16, m in {K,Q,V} ----------------
__global__ __launch_bounds__(256) void wprep_kernel(
    const float* __restrict__ Wk,
    const float* __restrict__ Wq,
    const float* __restrict__ Wv,
    unsigned short* __restrict__ wt)
{
    __shared__ float tile[64][65];
    const int m  = blockIdx.x >> 4;
    const int k0 = (blockIdx.x & 15) << 6;
    const float* __restrict__ W = (m == 0) ? Wk : (m == 1) ? Wq : Wv;
    const float qs = (m == 1) ? 0.125f * 1.44269504f : 1.0f;
    const int tid = threadIdx.x;
    const int c   = tid & 63;
    for (int i = tid >> 6; i < 64; i += 4)
        tile[i][c] = W[(size_t)(k0 + i) * NH + c];
    __syncthreads();
    const int i0 = (tid >> 6) * 16;
    unsigned short* dst = wt + ((size_t)m * 64 + c) * NC + k0 + i0;
    ushort8v a, b;
#pragma unroll
    for (int j = 0; j < 8; ++j) a[j] = f2bf(tile[i0 + j][c] * qs);
#pragma unroll
    for (int j = 0; j < 8; ++j) b[j] = f2bf(tile[i0 + 8 + j][c] * qs);
    *reinterpret_cast<ushort8v*>(dst)     = a;
    *reinterpret_cast<ushort8v*>(dst + 8) = b;
}

// ---------------- projection GEMM, reg-staged bf16 LDS (unchanged) --------
__global__ __launch_bounds__(256, 2) void proj_kernel(
    const float* __restrict__ x,
    const unsigned short* __restrict__ wt,
    unsigned short* __restrict__ ko,
    unsigned short* __restrict__ qo,
    unsigned short* __restrict__ vt)
{
    __shared__ unsigned short xsb[2][32 * 64];

    const int tid  = threadIdx.x;
    const int wid  = tid >> 6;
    const int lane = tid & 63;
    const int l15  = lane & 15;
    const int hi   = lane >> 4;
    const int t0   = blockIdx.x << 5;

    const int srow = tid >> 3;
    const int sg   = tid & 7;
    const int ssw  = sg ^ (srow & 7);
    const float* __restrict__ xsrc = x + (size_t)(t0 + srow) * NC + sg * 8;
    unsigned short* const sdst0 = &xsb[0][srow * 64 + ssw * 8];
    unsigned short* const sdst1 = &xsb[1][srow * 64 + ssw * 8];

    const unsigned short* wp[3];
    int mm[3], hr[3];
#pragma unroll
    for (int f = 0; f < 3; ++f) {
        const int hc = wid * 48 + f * 16;
        mm[f] = hc >> 6;
        hr[f] = hc & 63;
        wp[f] = wt + ((size_t)(mm[f] * 64 + hr[f] + l15)) * NC + hi * 8;
    }

    f32x4 acc[2][3];
#pragma unroll
    for (int mf = 0; mf < 2; ++mf)
#pragma unroll
        for (int f = 0; f < 3; ++f) acc[mf][f] = (f32x4){0.f, 0.f, 0.f, 0.f};

    auto XWRITE = [&](unsigned short* dst, const f32x4& a, const f32x4& b) {
        ushort8v pk;
        pk[0] = f2bf(a[0]); pk[1] = f2bf(a[1]);
        pk[2] = f2bf(a[2]); pk[3] = f2bf(a[3]);
        pk[4] = f2bf(b[0]); pk[5] = f2bf(b[1]);
        pk[6] = f2bf(b[2]); pk[7] = f2bf(b[3]);
        *reinterpret_cast<ushort8v*>(dst) = pk;
    };

    auto COMPUTE = [&](int bi, int ck) {
        short8 xf[2][2];
#pragma unroll
        for (int mf = 0; mf < 2; ++mf) {
            const int row = mf * 16 + l15;
#pragma unroll
            for (int ks = 0; ks < 2; ++ks) {
                const int sw = (ks * 4 + hi) ^ (row & 7);
                xf[mf][ks] = *reinterpret_cast<const short8*>(
                    &xsb[bi][row * 64 + sw * 8]);
            }
        }
#pragma unroll
        for (int f = 0; f < 3; ++f) {
#pragma unroll
            for (int ks = 0; ks < 2; ++ks) {
                const short8 wf = *reinterpret_cast<const short8*>(
                    wp[f] + ck * 64 + ks * 32);
                if (mm[f] == 2) {
#pragma unroll
                    for (int mf = 0; mf < 2; ++mf)
                        acc[mf][f] = __builtin_amdgcn_mfma_f32_16x16x32_bf16(
                            xf[mf][ks], wf, acc[mf][f], 0, 0, 0);
                } else {
#pragma unroll
                    for (int mf = 0; mf < 2; ++mf)
                        acc[mf][f] = __builtin_amdgcn_mfma_f32_16x16x32_bf16(
                            wf, xf[mf][ks], acc[mf][f], 0, 0, 0);
                }
            }
        }
    };

    {
        const f32x4 a = *reinterpret_cast<const f32x4*>(xsrc);
        const f32x4 b = *reinterpret_cast<const f32x4*>(xsrc + 4);
        XWRITE(sdst0, a, b);
    }
    __syncthreads();

    for (int ck = 0; ck < 16; ++ck) {
        const int cur = ck & 1;
        f32x4 na, nb;
        if (ck < 15) {
            const float* p = xsrc + (ck + 1) * 64;
            na = *reinterpret_cast<const f32x4*>(p);
            nb = *reinterpret_cast<const f32x4*>(p + 4);
        }
        COMPUTE(cur, ck);
        if (ck < 15) XWRITE(cur ? sdst0 : sdst1, na, nb);
        __syncthreads();
    }

    const int b  = t0 >> 12;
    const int tl = t0 & (NT - 1);
#pragma unroll
    for (int f = 0; f < 3; ++f) {
#pragma unroll
        for (int mf = 0; mf < 2; ++mf) {
            const f32x4 a = acc[mf][f];
            ushort4v pk;
            pk[0] = f2bf(a[0]); pk[1] = f2bf(a[1]);
            pk[2] = f2bf(a[2]); pk[3] = f2bf(a[3]);
            if (mm[f] == 2) {
                unsigned short* d = vt + ((size_t)(b * NH + hr[f] + l15)) * NT
                                       + tl + mf * 16 + hi * 4;
                *reinterpret_cast<ushort4v*>(d) = pk;
            } else {
                unsigned short* o = (mm[f] == 0) ? ko : qo;
                unsigned short* d = o + (size_t)(t0 + mf * 16 + l15) * NH
                                      + hr[f] + hi * 4;
                *reinterpret_cast<ushort4v*>(d) = pk;
            }
        }
    }
}

// ---------------- MFMA flash attention, shared-LDS K/V, chunked ----------
// Block = 128 q-rows (8 waves x 16) x one 8-tile KV chunk. K/V tiles staged
// ONCE in LDS (reg-staged, XOR-swizzled) and consumed by all 8 waves ->
// 8x less L2 traffic per tile. 576 equal blocks (144 chunks x 4 batches),
// partial (m,l,O) per chunk -> workspace; comb_kernel merges <=8 chunks.
// Chunk math per batch: qtile qi (128 rows) spans n=2qi+2 KV tiles,
// nch(qi)=(qi>>2)+1 chunks, base(qi)=qi+2g(g-1)+r*g (g=qi>>2, r=qi&3).
__global__ __launch_bounds__(512) void attn_kernel(
    const unsigned short* __restrict__ kin,
    const unsigned short* __restrict__ qin,
    const unsigned short* __restrict__ vt,
    float* __restrict__ part)
{
    __shared__ unsigned short ksb[2][64 * 64];   // 2 x 8 KB, swizzled
    __shared__ unsigned short vsb[2][64 * 64];   // 2 x 8 KB, swizzled
    __shared__ unsigned short p_lds[8][16 * 72]; // 18 KB

    const int tid  = threadIdx.x;
    const int wid  = tid >> 6;
    const int lane = tid & 63;
    const int q15  = lane & 15;
    const int hi   = lane >> 4;

    const int bid  = blockIdx.x;
    const int xcd  = bid & 7;
    const int b    = xcd >> 1;                          // batch pinned to XCD pair
    const int clin = ((bid >> 3) << 1) | (xcd & 1);     // 0..143
    const int c    = 143 - clin;                        // heavy-first

    // invert base(): find qi with base(qi) <= c
    int qi = 0, basei = 0;
    for (int t = 31; t >= 0; --t) {
        const int g = t >> 2, r = t & 3;
        const int bs = t + 2 * g * (g - 1) + r * g;
        if (bs <= c) { qi = t; basei = bs; break; }
    }
    const int k     = c - basei;                 // chunk within q-tile
    const int n_blk = 2 * qi + 2;
    const int jb0   = k * 8;
    const int jend  = min(jb0 + 8, n_blk);       // block-uniform loop bound
    const int n_w   = 2 * qi + 1 + (wid >> 2);   // per-wave causal extent

    const unsigned short* kb = kin + (size_t)b * NT * NH;
    const unsigned short* qb = qin + (size_t)b * NT * NH;
    const unsigned short* vb = vt  + (size_t)b * NH * NT;

    const int gq = qi * 128 + wid * 16 + q15;    // q row (within batch)

    short8 qf0, qf1;
    {
        const unsigned short* qrow = qb + (size_t)gq * NH + hi * 8;
        qf0 = *reinterpret_cast<const short8*>(qrow);
        qf1 = *reinterpret_cast<const short8*>(qrow + 32);
    }

    // staging geometry: thread owns one 16B group of each 64x64 tile
    const int srow = tid >> 3;                   // 0..63
    const int sg   = tid & 7;                    // 0..7
    const int sdst = srow * 64 + (sg ^ (srow & 7)) * 8;
    const unsigned short* kstat = kb + (size_t)srow * NH + sg * 8;  // + jb*4096
    const unsigned short* vstat = vb + (size_t)srow * NT + sg * 8;  // + jb*64

    f32x4 ot[4];
#pragma unroll
    for (int i = 0; i < 4; ++i) ot[i] = (f32x4){0.f, 0.f, 0.f, 0.f};
    float m = 0.f, lp = 0.f;                     // defer-max; log2 domain

    // prologue: stage tile jb0
    {
        const short8 kr = *reinterpret_cast<const short8*>(kstat + (size_t)jb0 * 4096);
        const short8 vr = *reinterpret_cast<const short8*>(vstat + jb0 * 64);
        *reinterpret_cast<short8*>(&ksb[0][sdst]) = kr;
        *reinterpret_cast<short8*>(&vsb[0][sdst]) = vr;
    }
    __syncthreads();

    int cur = 0;
    for (int jb = jb0; jb < jend; ++jb) {
        const bool more = (jb + 1 < jend);
        short8 knx, vnx;
        if (more) {                              // issue next-tile loads early
            knx = *reinterpret_cast<const short8*>(kstat + (size_t)(jb + 1) * 4096);
            vnx = *reinterpret_cast<const short8*>(vstat + (jb + 1) * 64);
        }

        if (jb < n_w) {                          // wave-uniform skip
            const int kv0 = jb << 6;
            const int r7  = q15 & 7;

            // ---- S^T = K . Q^T (K from LDS, swizzled) ----
            f32x4 st[4];
#pragma unroll
            for (int kt = 0; kt < 4; ++kt) {
                const int rb = (kt * 16 + q15) * 64;
                const short8 ka0 = *reinterpret_cast<const short8*>(
                    &ksb[cur][rb + ((hi ^ r7) * 8)]);
                const short8 ka1 = *reinterpret_cast<const short8*>(
                    &ksb[cur][rb + (((4 + hi) ^ r7) * 8)]);
                f32x4 acc = (f32x4){0.f, 0.f, 0.f, 0.f};
                acc = __builtin_amdgcn_mfma_f32_16x16x32_bf16(ka0, qf0, acc, 0, 0, 0);
                acc = __builtin_amdgcn_mfma_f32_16x16x32_bf16(ka1, qf1, acc, 0, 0, 0);
                st[kt] = acc;
            }

            // ---- mask (diagonal tile only) + per-lane max ----
            float tmax4 = -INFINITY;
            if (jb == n_w - 1) {
#pragma unroll
                for (int kt = 0; kt < 4; ++kt)
#pragma unroll
                    for (int r = 0; r < 4; ++r) {
                        const int gk = kv0 + kt * 16 + hi * 4 + r;
                        const float s = (gk <= gq) ? st[kt][r] : -INFINITY;
                        st[kt][r] = s;
                        tmax4 = fmaxf(tmax4, s);
                    }
            } else {
#pragma unroll
                for (int kt = 0; kt < 4; ++kt)
#pragma unroll
                    for (int r = 0; r < 4; ++r)
                        tmax4 = fmaxf(tmax4, st[kt][r]);
            }

            // ---- defer-max rescale (rare) ----
            if (!__all(tmax4 <= m + 11.5f)) {
                float tm = fmaxf(tmax4, __shfl_xor(tmax4, 16));
                tm = fmaxf(tm, __shfl_xor(tm, 32));
                const float mnew = fmaxf(m, tm);
                const float corr = __builtin_amdgcn_exp2f(m - mnew);
                lp *= corr;
#pragma unroll
                for (int i = 0; i < 4; ++i) {
                    ot[i][0] *= corr; ot[i][1] *= corr;
                    ot[i][2] *= corr; ot[i][3] *= corr;
                }
                m = mnew;
            }

            // ---- P = exp2(S - m) -> p_lds (bf16) ----
#pragma unroll
            for (int kt = 0; kt < 4; ++kt) {
                const float p0 = __builtin_amdgcn_exp2f(st[kt][0] - m);
                const float p1 = __builtin_amdgcn_exp2f(st[kt][1] - m);
                const float p2 = __builtin_amdgcn_exp2f(st[kt][2] - m);
                const float p3 = __builtin_amdgcn_exp2f(st[kt][3] - m);
                lp += (p0 + p1) + (p2 + p3);
                ushort4v pk;
                pk[0] = f2bf(p0); pk[1] = f2bf(p1);
                pk[2] = f2bf(p2); pk[3] = f2bf(p3);
                *reinterpret_cast<ushort4v*>(&p_lds[wid][q15 * 72 + kt * 16 + hi * 4]) = pk;
            }

            // ---- O^T += V^T . P^T (V from LDS, swizzled) ----
            const short8 pb0 = *reinterpret_cast<const short8*>(&p_lds[wid][q15 * 72 + hi * 8]);
            const short8 pb1 = *reinterpret_cast<const short8*>(&p_lds[wid][q15 * 72 + 32 + hi * 8]);
#pragma unroll
            for (int ht = 0; ht < 4; ++ht) {
                const int rb = (ht * 16 + q15) * 64;
                const short8 va0 = *reinterpret_cast<const short8*>(
                    &vsb[cur][rb + ((hi ^ r7) * 8)]);
                const short8 va1 = *reinterpret_cast<const short8*>(
                    &vsb[cur][rb + (((4 + hi) ^ r7) * 8)]);
                ot[ht] = __builtin_amdgcn_mfma_f32_16x16x32_bf16(va0, pb0, ot[ht], 0, 0, 0);
                ot[ht] = __builtin_amdgcn_mfma_f32_16x16x32_bf16(va1, pb1, ot[ht], 0, 0, 0);
            }
        }

        if (more) {
            *reinterpret_cast<short8*>(&ksb[cur ^ 1][sdst]) = knx;
            *reinterpret_cast<short8*>(&vsb[cur ^ 1][sdst]) = vnx;
        }
        __syncthreads();                          // block-uniform
        cur ^= 1;
    }

    // ---- write partial (m, l, O) for this (block, wave, row) ----
    float l = lp + __shfl_xor(lp, 16);
    l += __shfl_xor(l, 32);
    float* pp = part + (((size_t)b * 144 + c) * 128 + wid * 16 + q15) * 68;
#pragma unroll
    for (int ht = 0; ht < 4; ++ht)
        *reinterpret_cast<f32x4*>(pp + ht * 16 + hi * 4) = ot[ht];
    if (hi == 0) { pp[64] = m; pp[65] = l; }
}

// ---------------- combine chunk partials ----------------
__global__ __launch_bounds__(256) void comb_kernel(
    const float* __restrict__ part,
    float* __restrict__ outp)
{
    const int tid = threadIdx.x;
    const int bid = blockIdx.x;
    const int b   = bid >> 10;
    const int lr  = ((bid & 1023) << 2) + (tid >> 6);   // row in batch
    const int h   = tid & 63;
    const int qi  = lr >> 7;
    const int g   = qi >> 2, r = qi & 3;
    const int basei = qi + 2 * g * (g - 1) + r * g;
    const int nch   = (qi >> 2) + 1;
    const float* p0 = part + (((size_t)b * 144 + basei) * 128 + (lr & 127)) * 68;

    float mg = -INFINITY;
    for (int ch = 0; ch < nch; ++ch)
        mg = fmaxf(mg, p0[(size_t)ch * 128 * 68 + 64]);
    float L = 0.f, o = 0.f;
    for (int ch = 0; ch < nch; ++ch) {
        const float* pc = p0 + (size_t)ch * 128 * 68;
        const float w = __builtin_amdgcn_exp2f(pc[64] - mg);
        L += w * pc[65];
        o += w * pc[h];
    }
    outp[((size_t)b * NT + lr) * NH + h] = o / L;
}

extern "C" void kernel_launch(void* const* d_in, const int* in_sizes, int n_in,
                              void* d_out, int out_size, void* d_ws, size_t ws_size,
                              hipStream_t stream) {
    const float* x  = (const float*)d_in[0];
    const float* Wk = (const float*)d_in[1];
    const float* Wq = (const float*)d_in[2];
    const float* Wv = (const float*)d_in[3];
    float* out = (float*)d_out;

    unsigned short* kbuf = (unsigned short*)d_ws;              // [B*T][64] bf16
    unsigned short* qbuf = kbuf + (size_t)NB * NT * NH;        // [B*T][64] bf16
    unsigned short* vtbf = qbuf + (size_t)NB * NT * NH;        // [B][64][T] bf16
    unsigned short* wtbf = vtbf + (size_t)NB * NT * NH;        // [3][64][1024] bf16
    float* part = (float*)(wtbf + (size_t)3 * 64 * NC);        // [B][144][128][68] f32 (~20 MB; total ws ~33 MB)

    wprep_kernel<<<48, 256, 0, stream>>>(Wk, Wq, Wv, wtbf);
    proj_kernel<<<NB * NT / 32, 256, 0, stream>>>(x, wtbf, kbuf, qbuf, vtbf);
    attn_kernel<<<576, 512, 0, stream>>>(kbuf, qbuf, vtbf, part);
    comb_kernel<<<4096, 256, 0, stream>>>(part, out);
}